// Round 7
// baseline (685.190 us; speedup 1.0000x reference)
//
#include <hip/hip_runtime.h>
#include <hip/hip_bf16.h>
#include <math.h>

// Problem constants (match reference)
#define V_SIZE 100000
#define D_DIM  256
#define S_DIM  128
#define H_DIM  512
#define B_SIZE 8192
#define K_NEG  32
#define NR     60000           // NUM_REGULAR
#define NMOD   (V_SIZE - NR)   // 40000 modified words

// MLP tiling (TM=48 = best; TM=32 regressed -> keep 48)
#define TM     48              // rows per block (3 x 16)
#define CBLK   834             // ceil(40000/48)
#define UBLK   171             // ceil(8192/48)
#define MC_PAD (CBLK * TM)     // 40032 padded c-side rows
#define MU_PAD (UBLK * TM)     // 8208  padded u-side rows
// LDS H row stride (shorts). 516: layer-1 b16 writes land 2 lanes/bank
// (free); 1032-B rows keep 8-B alignment for ds_read_b64 in layer 2.
#define HPAD   516

typedef __attribute__((ext_vector_type(8))) short bf16x8;   // 8 bf16 = 4 VGPRs
typedef __attribute__((ext_vector_type(8))) unsigned short u16x8;
typedef __attribute__((ext_vector_type(4))) float f32x4;

static __device__ __forceinline__ short f2bf(float f) {
    unsigned u = __builtin_bit_cast(unsigned, f);
    unsigned r = (u + 0x7fffu + ((u >> 16) & 1u)) >> 16;   // RNE
    return (short)r;
}
static __device__ __forceinline__ float bf2f(unsigned short h) {
    return __builtin_bit_cast(float, ((unsigned)h) << 16);
}

// ---------------------------------------------------------------------------
// Vall STORAGE (bf16, permuted columns), rows 0..100032:
//   rows [0,60000)       = bf16(v_emb)            (written by prep)
//   rows [60000,100032)  = MLP c-table (padded)   (written by fused_mlp)
//   storage pos p = wv*64 + fr*4 + ni  <->  logical col c = wv*64 + ni*16 + fr
// Dot products are permutation-invariant; score indexes Vall[ix] directly.
// Ubuf (u-side MLP rows) uses the same permuted layout.
// ---------------------------------------------------------------------------

#define N_VC   (NR * D_DIM / 4)               // 3,840,000
#define N_CONV (MC_PAD * S_DIM / 4)           // 1,281,024
#define N_XU   (MU_PAD * S_DIM / 4)           //   262,656
#define N_TR   393216

__global__ __launch_bounds__(256) void prep_kernel(
    const float* __restrict__ stoich, const int* __restrict__ pos_u,
    const float* __restrict__ v_emb,
    const float* __restrict__ tw1, const float* __restrict__ cw1,
    const float* __restrict__ tw2, const float* __restrict__ cw2,
    short* __restrict__ vall,
    short* __restrict__ xc, short* __restrict__ xu,
    short* __restrict__ W1T_t, short* __restrict__ W1T_c,
    short* __restrict__ W2T_t, short* __restrict__ W2T_c,
    unsigned int* __restrict__ cnt)
{
    int t = blockIdx.x * 256 + threadIdx.x;
    if (t == 0) *cnt = 0u;                    // ticket for score's final reduce
    if (t < N_VC) {
        // v_emb row -> bf16 permuted storage. Thread covers storage positions
        // p = (t&63)*4 .. +3 (ni=0..3) of row r: logical cols wv*64+{0,16,32,48}+fr.
        int r  = t >> 6;
        int fr = t & 15;
        int wv = (t & 63) >> 4;
        const float* rp = v_emb + (size_t)r * D_DIM + wv * 64 + fr;
        short4 o;
        o.x = f2bf(rp[0]); o.y = f2bf(rp[16]); o.z = f2bf(rp[32]); o.w = f2bf(rp[48]);
        ((short4*)vall)[t] = o;
        return;
    }
    t -= N_VC;
    if (t < N_CONV + N_XU) {
        // A-side fragment-linear bf16 (short4 per thread, j0 in {0,4})
        const bool cside = t < N_CONV;
        const int e    = (cside ? t : t - N_CONV) * 4;
        const int j0   = e & 7;
        const int lane = (e >> 3) & 63;
        const int ks   = (e >> 9) & 3;
        const int rt   = e >> 11;
        const int row  = rt * 16 + (lane & 15);
        const int k    = ks * 32 + (lane >> 4) * 8 + j0;
        short4 o = {0, 0, 0, 0};
        if (cside) {
            if (row < NMOD) {
                const float4 v = *(const float4*)(stoich + (size_t)(NR + row) * S_DIM + k);
                o.x = f2bf(v.x); o.y = f2bf(v.y); o.z = f2bf(v.z); o.w = f2bf(v.w);
            }
            ((short4*)xc)[t] = o;
        } else {
            if (row < B_SIZE) {
                int pu = pos_u[row];
                const float4 v = *(const float4*)(stoich + (size_t)pu * S_DIM + k);
                o.x = f2bf(v.x); o.y = f2bf(v.y); o.z = f2bf(v.z); o.w = f2bf(v.w);
            }
            ((short4*)xu)[t - N_CONV] = o;
        }
    } else {
        int t3 = t - (N_CONV + N_XU);                 // [0, 393216)
        if (t3 < 131072) {                            // W1 pair (65536 each)
            const float* src = (t3 < 65536) ? tw1 : cw1;
            short*       dst = (t3 < 65536) ? W1T_t : W1T_c;
            int t4 = t3 & 65535;
            int j = t4 & 7, lane = (t4 >> 3) & 63;
            int nt = (t4 >> 9) & 31, ks = (t4 >> 14) & 3;
            int k = ks * 32 + (lane >> 4) * 8 + j, n = nt * 16 + (lane & 15);
            dst[t4] = f2bf(src[(size_t)k * H_DIM + n]);
        } else {                                      // W2 pair (131072 each)
            int t5 = t3 - 131072;
            const float* src = (t5 < 131072) ? tw2 : cw2;
            short*       dst = (t5 < 131072) ? W2T_t : W2T_c;
            int t4 = t5 & 131071;
            int j = t4 & 7, lane = (t4 >> 3) & 63;
            int nt = (t4 >> 9) & 15, ks = (t4 >> 13) & 15;
            int k = ks * 32 + (lane >> 4) * 8 + j, n = nt * 16 + (lane & 15);
            dst[t4] = f2bf(src[(size_t)k * D_DIM + n]);
        }
    }
}

// ---------------------------------------------------------------------------
// Fused 2-layer MLP. outF[M][256] bf16 (permuted) = relu(A@W1+b1)@W2+b2.
// Block = 4 waves, TM=48 rows. Layer 1: hand-scheduled 3-buffer depth-2
// B-fragment pipeline across all 8 ks-steps (both halves seamless; next
// half's first frags load under current half's last MFMAs). b1 hoisted.
// Layer 2: depth-3 global B prefetch, first 3 issued before the barrier
// and before the half-1 epilogue. Epilogue: short4 permuted bf16 stores.
// Verified MFMA layouts (m89/m91): A[m=lane&15][k=q*8+j]; B^T row (lane&15)
// supplies B[k][n=lane&15]; D: col=lane&15, row=q*4+reg.
// ---------------------------------------------------------------------------
__global__ __launch_bounds__(256, 3) void fused_mlp_kernel(
    const short* __restrict__ Xc,  const short* __restrict__ W1c,
    const float* __restrict__ b1c, const short* __restrict__ W2c,
    const float* __restrict__ b2c, short* __restrict__ outc,
    const short* __restrict__ Xu,  const short* __restrict__ W1u,
    const float* __restrict__ b1u, const short* __restrict__ W2u,
    const float* __restrict__ b2u, short* __restrict__ outu)
{
    __shared__ short sH[TM * HPAD];   // 49,536 B -> 3 blocks/CU

    const int blk = blockIdx.x;
    const short *A, *W1T, *W2T; const float *b1, *b2; short* out;
    int m0, rtb;
    if (blk < CBLK) { A = Xc; W1T = W1c; b1 = b1c; W2T = W2c; b2 = b2c;
                      out = outc; m0 = blk * TM; rtb = blk * 3; }
    else            { A = Xu; W1T = W1u; b1 = b1u; W2T = W2u; b2 = b2u;
                      out = outu; m0 = (blk - CBLK) * TM; rtb = (blk - CBLK) * 3; }

    const int lane = threadIdx.x & 63;
    const int wv   = threadIdx.x >> 6;
    const int fr   = lane & 15;
    const int q    = lane >> 4;

    // hoisted b1 biases (both halves x 4 ni)
    float b1v[8];
    #pragma unroll
    for (int i = 0; i < 8; ++i)
        b1v[i] = b1[(wv * 8 + i) * 16 + fr];

    // ---- layer 1 ----
    // A fragments: XF[((rtb+mi)*4 + ks)*512 + lane*8], contiguous per wave
    const short* Ap  = A + (size_t)rtb * 2048 + lane * 8;
    const short* Bp0 = W1T + (size_t)(wv * 8) * 512 + lane * 8;      // half 0
    const short* Bp1 = W1T + (size_t)(wv * 8 + 4) * 512 + lane * 8;  // half 1
    bf16x8 af[4][3];
    #pragma unroll
    for (int ks = 0; ks < 4; ++ks)
        #pragma unroll
        for (int mi = 0; mi < 3; ++mi)
            af[ks][mi] = *(const bf16x8*)(Ap + mi * 2048 + ks * 512);

    bf16x8 bX[4], bY[4], bZ[4];
    #define LOAD_B1(bp, ks, dst)                                              \
        _Pragma("unroll")                                                     \
        for (int ni = 0; ni < 4; ++ni)                                        \
            dst[ni] = *(const bf16x8*)((bp) + (ks) * 16384 + ni * 512);
    #define MFMA12(ks, bsrc, accv)                                            \
        _Pragma("unroll")                                                     \
        for (int mi = 0; mi < 3; ++mi)                                        \
            _Pragma("unroll")                                                 \
            for (int ni = 0; ni < 4; ++ni)                                    \
                accv[mi][ni] = __builtin_amdgcn_mfma_f32_16x16x32_bf16(       \
                    af[ks][mi], bsrc[ni], accv[mi][ni], 0, 0, 0);
    #define EPI1(h, accv)                                                     \
        _Pragma("unroll")                                                     \
        for (int ni = 0; ni < 4; ++ni) {                                      \
            int c = (wv * 8 + (h) * 4 + ni) * 16 + fr;                        \
            float bv = b1v[(h) * 4 + ni];                                     \
            _Pragma("unroll")                                                 \
            for (int mi = 0; mi < 3; ++mi)                                    \
                _Pragma("unroll")                                             \
                for (int r = 0; r < 4; ++r)                                   \
                    sH[(mi * 16 + q * 4 + r) * HPAD + c] =                    \
                        f2bf(fmaxf(accv[mi][ni][r] + bv, 0.f));               \
        }

    LOAD_B1(Bp0, 0, bX);
    LOAD_B1(Bp0, 1, bY);
    {
        f32x4 acc[3][4] = {};
        LOAD_B1(Bp0, 2, bZ);  MFMA12(0, bX, acc);
        LOAD_B1(Bp0, 3, bX);  MFMA12(1, bY, acc);
        LOAD_B1(Bp1, 0, bY);  MFMA12(2, bZ, acc);
        LOAD_B1(Bp1, 1, bZ);  MFMA12(3, bX, acc);
        EPI1(0, acc);
    }
    // layer-2 B prefetch pointers (issue first 3 before half-1 epilogue)
    const short* Bp2 = W2T + (size_t)(wv * 4) * 512 + lane * 8;
    f32x4 acc2[3][4] = {};
    bf16x8 bA[4], bB[4], bC[4], bD[4], aA[3], aB[3];
    #define LOAD_B2(ks, dst)                                                  \
        _Pragma("unroll")                                                     \
        for (int ni = 0; ni < 4; ++ni)                                        \
            dst[ni] = *(const bf16x8*)(Bp2 + (ks) * 8192 + ni * 512);
    {
        f32x4 acc[3][4] = {};
        LOAD_B1(Bp1, 2, bX);  MFMA12(0, bY, acc);
        LOAD_B1(Bp1, 3, bY);  MFMA12(1, bZ, acc);
        MFMA12(2, bX, acc);
        MFMA12(3, bY, acc);
        LOAD_B2(0, bA);
        LOAD_B2(1, bB);
        LOAD_B2(2, bC);
        EPI1(1, acc);
    }
    #undef LOAD_B1
    #undef MFMA12
    #undef EPI1

    __syncthreads();

    // ---- layer 2: depth-3 global B prefetch, depth-1 LDS A, 16 K-steps ----
    #define LOAD_A(ks, dst)                                                   \
        _Pragma("unroll")                                                     \
        for (int mi = 0; mi < 3; ++mi) {                                      \
            const short* hp = &sH[(mi * 16 + fr) * HPAD + (ks) * 32 + q * 8]; \
            short4 lo = *(const short4*)hp;                                   \
            short4 hi = *(const short4*)(hp + 4);                             \
            bf16x8 v;                                                         \
            v[0] = lo.x; v[1] = lo.y; v[2] = lo.z; v[3] = lo.w;               \
            v[4] = hi.x; v[5] = hi.y; v[6] = hi.z; v[7] = hi.w;               \
            dst[mi] = v;                                                      \
        }

    LOAD_A(0, aA);
    #pragma unroll
    for (int ks = 0; ks < 16; ++ks) {
        if (ks < 13) { LOAD_B2(ks + 3, bD); }
        if (ks < 15) { LOAD_A(ks + 1, aB); }
        #pragma unroll
        for (int mi = 0; mi < 3; ++mi)
            #pragma unroll
            for (int ni = 0; ni < 4; ++ni)
                acc2[mi][ni] = __builtin_amdgcn_mfma_f32_16x16x32_bf16(
                    aA[mi], bA[ni], acc2[mi][ni], 0, 0, 0);
        if (ks < 15) {
            #pragma unroll
            for (int i = 0; i < 4; ++i) { bA[i] = bB[i]; bB[i] = bC[i]; bC[i] = bD[i]; }
            #pragma unroll
            for (int i = 0; i < 3; ++i) aA[i] = aB[i];
        }
    }
    #undef LOAD_A
    #undef LOAD_B2

    // epilogue: bf16 short4 stores in permuted storage order
    float bv[4];
    #pragma unroll
    for (int ni = 0; ni < 4; ++ni)
        bv[ni] = b2[wv * 64 + ni * 16 + fr];
    #pragma unroll
    for (int mi = 0; mi < 3; ++mi)
        #pragma unroll
        for (int r = 0; r < 4; ++r) {
            int row = m0 + mi * 16 + q * 4 + r;
            short4 s;
            s.x = f2bf(acc2[mi][0][r] + bv[0]);
            s.y = f2bf(acc2[mi][1][r] + bv[1]);
            s.z = f2bf(acc2[mi][2][r] + bv[2]);
            s.w = f2bf(acc2[mi][3][r] + bv[3]);
            *(short4*)(out + (size_t)row * D_DIM + wv * 64 + fr * 4) = s;
        }
}

// ---------------------------------------------------------------------------
// Scoring + final reduce (last-block ticket). One block (4 waves) per
// sample; branchless V-side from Vall (bf16 permuted); all row loads issued
// up front. Writers release partials (agent scope); the last block acquires
// and reduces -> out[0]. Counter zeroed by prep each iteration.
// total_b = 2*( -logsig(clip(eu.ev)) - sum_k logsig(-clip(env_k.eu)) )
// ---------------------------------------------------------------------------
__device__ __forceinline__ float logsig_fast(float x) {
    float t = __expf(-fabsf(x));
    return fminf(x, 0.f) - __logf(1.f + t);
}
__device__ __forceinline__ float clip10(float x) {
    return fminf(fmaxf(x, -10.f), 10.f);
}

__global__ __launch_bounds__(256) void score_kernel(
    const int*   __restrict__ pos_u,
    const int*   __restrict__ pos_v,
    const int*   __restrict__ neg_v,
    const float* __restrict__ u_emb,
    const unsigned short* __restrict__ Vall,   // [100032][256] bf16, permuted
    const unsigned short* __restrict__ Ubuf,   // [MU_PAD][256] bf16, permuted
    float* __restrict__ partials,              // [B]
    unsigned int* __restrict__ cnt,
    float* __restrict__ out)
{
    const int b    = blockIdx.x;
    const int lane = threadIdx.x & 63;
    const int wv   = threadIdx.x >> 6;
    const int g    = lane >> 4;
    const int l    = lane & 15;
    const int w64  = (l >> 2) * 64;        // storage 64-col block
    const int s4   = (l & 3) * 4;          // fr base within block

    // Issue all row loads up front (one latency exposure).
    const int* nv = neg_v + (size_t)b * K_NEG + wv * 8;
    int ix0 = nv[g];
    int ix1 = nv[4 + g];
    const unsigned short* r0p = Vall + (size_t)ix0 * D_DIM + l * 16;
    const unsigned short* r1p = Vall + (size_t)ix1 * D_DIM + l * 16;
    u16x8 r0a = *(const u16x8*)r0p;
    u16x8 r0b = *(const u16x8*)(r0p + 8);
    u16x8 r1a = *(const u16x8*)r1p;
    u16x8 r1b = *(const u16x8*)(r1p + 8);
    u16x8 rpa, rpb;
    if (wv == 0) {
        const unsigned short* rpp = Vall + (size_t)pos_v[b] * D_DIM + l * 16;
        rpa = *(const u16x8*)rpp;
        rpb = *(const u16x8*)(rpp + 8);
    }

    // euf[i], i = j*4 + ni  <->  logical col w64 + ni*16 + s4 + j
    float euf[16];
    int pu = pos_u[b];
    if (pu < NR) {
        const float* eup = u_emb + (size_t)pu * D_DIM;
        #pragma unroll
        for (int n = 0; n < 4; ++n) {
            float4 v = *(const float4*)(eup + w64 + n * 16 + s4);
            euf[0 + n] = v.x; euf[4 + n] = v.y; euf[8 + n] = v.z; euf[12 + n] = v.w;
        }
    } else {
        const unsigned short* eup = Ubuf + (size_t)b * D_DIM + l * 16;
        u16x8 h0 = *(const u16x8*)eup;
        u16x8 h1 = *(const u16x8*)(eup + 8);
        #pragma unroll
        for (int i = 0; i < 8; ++i) { euf[i] = bf2f(h0[i]); euf[8 + i] = bf2f(h1[i]); }
    }

    float part = 0.f;

    float d0 = 0.f, d1 = 0.f;
    #pragma unroll
    for (int i = 0; i < 8; ++i) {
        d0 += euf[i] * bf2f(r0a[i]) + euf[8 + i] * bf2f(r0b[i]);
        d1 += euf[i] * bf2f(r1a[i]) + euf[8 + i] * bf2f(r1b[i]);
    }
    #pragma unroll
    for (int o = 1; o < 16; o <<= 1) {
        d0 += __shfl_xor(d0, o, 64);
        d1 += __shfl_xor(d1, o, 64);
    }
    part -= logsig_fast(-clip10(d0));
    part -= logsig_fast(-clip10(d1));

    if (wv == 0) {
        float dp = 0.f;
        #pragma unroll
        for (int i = 0; i < 8; ++i)
            dp += euf[i] * bf2f(rpa[i]) + euf[8 + i] * bf2f(rpb[i]);
        #pragma unroll
        for (int o = 1; o < 16; o <<= 1) dp += __shfl_xor(dp, o, 64);
        if (g == 0) part -= logsig_fast(clip10(dp));
    }

    float ws = part;
    #pragma unroll
    for (int o = 32; o; o >>= 1) ws += __shfl_xor(ws, o, 64);
    __shared__ float sp[4];
    __shared__ int lastFlag;
    if (lane == 0) sp[wv] = ws * 0.0625f;
    __syncthreads();
    if (threadIdx.x == 0) {
        __hip_atomic_store(&partials[b], sp[0] + sp[1] + sp[2] + sp[3],
                           __ATOMIC_RELEASE, __HIP_MEMORY_SCOPE_AGENT);
        unsigned old = __hip_atomic_fetch_add(cnt, 1u, __ATOMIC_ACQ_REL,
                                              __HIP_MEMORY_SCOPE_AGENT);
        lastFlag = (old == (unsigned)(B_SIZE - 1));
    }
    __syncthreads();
    if (lastFlag) {
        float s = 0.f;
        for (int i = threadIdx.x; i < B_SIZE; i += 256)
            s += __hip_atomic_load(&partials[i], __ATOMIC_RELAXED,
                                   __HIP_MEMORY_SCOPE_AGENT);
        #pragma unroll
        for (int o = 32; o; o >>= 1) s += __shfl_xor(s, o, 64);
        __shared__ float sr[4];
        if (lane == 0) sr[wv] = s;
        __syncthreads();
        if (threadIdx.x == 0)
            out[0] = (sr[0] + sr[1] + sr[2] + sr[3]) * (2.0f / (float)B_SIZE);
    }
}

// ---------------------------------------------------------------------------
extern "C" void kernel_launch(void* const* d_in, const int* in_sizes, int n_in,
                              void* d_out, int out_size, void* d_ws, size_t ws_size,
                              hipStream_t stream) {
    const int*   pos_u  = (const int*)  d_in[0];
    const int*   pos_v  = (const int*)  d_in[1];
    const int*   neg_v  = (const int*)  d_in[2];
    const float* u_emb  = (const float*)d_in[3];
    const float* v_emb  = (const float*)d_in[4];
    const float* stoich = (const float*)d_in[5];
    const float* tw1    = (const float*)d_in[6];
    const float* tb1    = (const float*)d_in[7];
    const float* tw2    = (const float*)d_in[8];
    const float* tb2    = (const float*)d_in[9];
    const float* cw1    = (const float*)d_in[10];
    const float* cb1    = (const float*)d_in[11];
    const float* cw2    = (const float*)d_in[12];
    const float* cb2    = (const float*)d_in[13];
    float* out = (float*)d_out;

    // workspace layout (bytes, 16B aligned)
    char* ws = (char*)d_ws;
    short* Xbf   = (short*)(ws);                      // MC_PAD*128*2  = 10,248,192
    short* Xu    = (short*)(ws + 10248192);           // MU_PAD*128*2  =  2,101,248
    short* W1T_t = (short*)(ws + 12349440);           //   512*128*2   =    131,072
    short* W1T_c = (short*)(ws + 12480512);           //                   131,072
    short* W2T_t = (short*)(ws + 12611584);           //   256*512*2   =    262,144
    short* W2T_c = (short*)(ws + 12873728);           //                   262,144
    short* Vall  = (short*)(ws + 13135872);           // 100032*256*2  = 51,216,384
    short* Ubuf  = (short*)(ws + 64352256);           // MU_PAD*256*2  =  4,202,496
    float* parts = (float*)(ws + 68554752);           //  8192*4
    unsigned int* cnt = (unsigned int*)(ws + 68587520);
    short* tab_c = Vall + (size_t)NR * D_DIM;         // MLP c-table inside Vall

    dim3 blk(256);

    // merged prep (1 launch): v_emb bf16 conversion + A-side + weights + cnt=0
    prep_kernel<<<dim3((N_VC + N_CONV + N_XU + N_TR) / 256), blk, 0, stream>>>(
        stoich, pos_u, v_emb, tw1, cw1, tw2, cw2,
        Vall, Xbf, Xu, W1T_t, W1T_c, W2T_t, W2T_c, cnt);

    // both fused MLP passes in one launch (c-side: 834 blocks, u-side: 171)
    fused_mlp_kernel<<<dim3(CBLK + UBLK), blk, 0, stream>>>(
        Xbf, W1T_c, cb1, W2T_c, cb2, tab_c,
        Xu,  W1T_t, tb1, W2T_t, tb2, Ubuf);

    // scoring + folded final reduction (last-block ticket)
    score_kernel<<<dim3(B_SIZE), blk, 0, stream>>>(
        pos_u, pos_v, neg_v, u_emb,
        (const unsigned short*)Vall, (const unsigned short*)Ubuf,
        parts, cnt, out);
}

// Round 8
// 295.306 us; speedup vs baseline: 2.3203x; 2.3203x over previous
//
#include <hip/hip_runtime.h>
#include <hip/hip_bf16.h>
#include <math.h>

// Problem constants (match reference)
#define V_SIZE 100000
#define D_DIM  256
#define S_DIM  128
#define H_DIM  512
#define B_SIZE 8192
#define K_NEG  32
#define NR     60000           // NUM_REGULAR
#define NMOD   (V_SIZE - NR)   // 40000 modified words

// MLP tiling (TM=48 = best; TM=32 regressed -> keep 48)
#define TM     48              // rows per block (3 x 16)
#define CBLK   834             // ceil(40000/48)
#define UBLK   171             // ceil(8192/48)
#define MC_PAD (CBLK * TM)     // 40032 padded c-side rows
#define MU_PAD (UBLK * TM)     // 8208  padded u-side rows
// LDS H row stride (shorts). 516: layer-1 b16 writes land 2 lanes/bank
// (free); 1032-B rows keep 8-B alignment for ds_read_b64 in layer 2.
#define HPAD   516

typedef __attribute__((ext_vector_type(8))) short bf16x8;   // 8 bf16 = 4 VGPRs
typedef __attribute__((ext_vector_type(8))) unsigned short u16x8;
typedef __attribute__((ext_vector_type(4))) float f32x4;

static __device__ __forceinline__ short f2bf(float f) {
    unsigned u = __builtin_bit_cast(unsigned, f);
    unsigned r = (u + 0x7fffu + ((u >> 16) & 1u)) >> 16;   // RNE
    return (short)r;
}
static __device__ __forceinline__ float bf2f(unsigned short h) {
    return __builtin_bit_cast(float, ((unsigned)h) << 16);
}

// ---------------------------------------------------------------------------
// Vall STORAGE (bf16, permuted columns), rows 0..100032:
//   rows [0,60000)       = bf16(v_emb)            (written by prep)
//   rows [60000,100032)  = MLP c-table (padded)   (written by fused_mlp)
//   storage pos p = wv*64 + fr*4 + ni  <->  logical col c = wv*64 + ni*16 + fr
// Dot products are permutation-invariant; score indexes Vall[ix] directly.
// Ubuf (u-side MLP rows) uses the same permuted layout.
// NOTE (round 7 lesson): NO agent-scope atomic reduction fold — per-XCD L2
// non-coherence makes agent-scope release/acq-rel cost ~50ns-scale cache
// maintenance per block (8192 blocks -> +400us). Separate reduce_kernel.
// ---------------------------------------------------------------------------

#define N_VC   (NR * D_DIM / 4)               // 3,840,000
#define N_CONV (MC_PAD * S_DIM / 4)           // 1,281,024
#define N_XU   (MU_PAD * S_DIM / 4)           //   262,656
#define N_TR   393216

__global__ __launch_bounds__(256) void prep_kernel(
    const float* __restrict__ stoich, const int* __restrict__ pos_u,
    const float* __restrict__ v_emb,
    const float* __restrict__ tw1, const float* __restrict__ cw1,
    const float* __restrict__ tw2, const float* __restrict__ cw2,
    short* __restrict__ vall,
    short* __restrict__ xc, short* __restrict__ xu,
    short* __restrict__ W1T_t, short* __restrict__ W1T_c,
    short* __restrict__ W2T_t, short* __restrict__ W2T_c)
{
    int t = blockIdx.x * 256 + threadIdx.x;
    if (t < N_VC) {
        // v_emb row -> bf16 permuted storage. Thread covers storage positions
        // p = (t&63)*4 .. +3 (ni=0..3) of row r: logical cols wv*64+{0,16,32,48}+fr.
        int r  = t >> 6;
        int fr = t & 15;
        int wv = (t & 63) >> 4;
        const float* rp = v_emb + (size_t)r * D_DIM + wv * 64 + fr;
        short4 o;
        o.x = f2bf(rp[0]); o.y = f2bf(rp[16]); o.z = f2bf(rp[32]); o.w = f2bf(rp[48]);
        ((short4*)vall)[t] = o;
        return;
    }
    t -= N_VC;
    if (t < N_CONV + N_XU) {
        // A-side fragment-linear bf16 (short4 per thread, j0 in {0,4})
        const bool cside = t < N_CONV;
        const int e    = (cside ? t : t - N_CONV) * 4;
        const int j0   = e & 7;
        const int lane = (e >> 3) & 63;
        const int ks   = (e >> 9) & 3;
        const int rt   = e >> 11;
        const int row  = rt * 16 + (lane & 15);
        const int k    = ks * 32 + (lane >> 4) * 8 + j0;
        short4 o = {0, 0, 0, 0};
        if (cside) {
            if (row < NMOD) {
                const float4 v = *(const float4*)(stoich + (size_t)(NR + row) * S_DIM + k);
                o.x = f2bf(v.x); o.y = f2bf(v.y); o.z = f2bf(v.z); o.w = f2bf(v.w);
            }
            ((short4*)xc)[t] = o;
        } else {
            if (row < B_SIZE) {
                int pu = pos_u[row];
                const float4 v = *(const float4*)(stoich + (size_t)pu * S_DIM + k);
                o.x = f2bf(v.x); o.y = f2bf(v.y); o.z = f2bf(v.z); o.w = f2bf(v.w);
            }
            ((short4*)xu)[t - N_CONV] = o;
        }
    } else {
        int t3 = t - (N_CONV + N_XU);                 // [0, 393216)
        if (t3 < 131072) {                            // W1 pair (65536 each)
            const float* src = (t3 < 65536) ? tw1 : cw1;
            short*       dst = (t3 < 65536) ? W1T_t : W1T_c;
            int t4 = t3 & 65535;
            int j = t4 & 7, lane = (t4 >> 3) & 63;
            int nt = (t4 >> 9) & 31, ks = (t4 >> 14) & 3;
            int k = ks * 32 + (lane >> 4) * 8 + j, n = nt * 16 + (lane & 15);
            dst[t4] = f2bf(src[(size_t)k * H_DIM + n]);
        } else {                                      // W2 pair (131072 each)
            int t5 = t3 - 131072;
            const float* src = (t5 < 131072) ? tw2 : cw2;
            short*       dst = (t5 < 131072) ? W2T_t : W2T_c;
            int t4 = t5 & 131071;
            int j = t4 & 7, lane = (t4 >> 3) & 63;
            int nt = (t4 >> 9) & 15, ks = (t4 >> 13) & 15;
            int k = ks * 32 + (lane >> 4) * 8 + j, n = nt * 16 + (lane & 15);
            dst[t4] = f2bf(src[(size_t)k * D_DIM + n]);
        }
    }
}

// ---------------------------------------------------------------------------
// Fused 2-layer MLP. outF[M][256] bf16 (permuted) = relu(A@W1+b1)@W2+b2.
// Block = 4 waves, TM=48 rows. Layer 1: hand-scheduled 3-buffer depth-2
// B-fragment pipeline across all 8 ks-steps (both halves seamless). b1
// hoisted. Layer 2: depth-3 global B prefetch, first 3 issued before the
// barrier and before the half-1 epilogue. Epilogue: short4 permuted stores.
// Verified MFMA layouts (m89/m91): A[m=lane&15][k=q*8+j]; B^T row (lane&15)
// supplies B[k][n=lane&15]; D: col=lane&15, row=q*4+reg.
// ---------------------------------------------------------------------------
__global__ __launch_bounds__(256, 3) void fused_mlp_kernel(
    const short* __restrict__ Xc,  const short* __restrict__ W1c,
    const float* __restrict__ b1c, const short* __restrict__ W2c,
    const float* __restrict__ b2c, short* __restrict__ outc,
    const short* __restrict__ Xu,  const short* __restrict__ W1u,
    const float* __restrict__ b1u, const short* __restrict__ W2u,
    const float* __restrict__ b2u, short* __restrict__ outu)
{
    __shared__ short sH[TM * HPAD];   // 49,536 B -> 3 blocks/CU

    const int blk = blockIdx.x;
    const short *A, *W1T, *W2T; const float *b1, *b2; short* out;
    int m0, rtb;
    if (blk < CBLK) { A = Xc; W1T = W1c; b1 = b1c; W2T = W2c; b2 = b2c;
                      out = outc; m0 = blk * TM; rtb = blk * 3; }
    else            { A = Xu; W1T = W1u; b1 = b1u; W2T = W2u; b2 = b2u;
                      out = outu; m0 = (blk - CBLK) * TM; rtb = (blk - CBLK) * 3; }

    const int lane = threadIdx.x & 63;
    const int wv   = threadIdx.x >> 6;
    const int fr   = lane & 15;
    const int q    = lane >> 4;

    // hoisted b1 biases (both halves x 4 ni)
    float b1v[8];
    #pragma unroll
    for (int i = 0; i < 8; ++i)
        b1v[i] = b1[(wv * 8 + i) * 16 + fr];

    // ---- layer 1 ----
    // A fragments: XF[((rtb+mi)*4 + ks)*512 + lane*8], contiguous per wave
    const short* Ap  = A + (size_t)rtb * 2048 + lane * 8;
    const short* Bp0 = W1T + (size_t)(wv * 8) * 512 + lane * 8;      // half 0
    const short* Bp1 = W1T + (size_t)(wv * 8 + 4) * 512 + lane * 8;  // half 1
    bf16x8 af[4][3];
    #pragma unroll
    for (int ks = 0; ks < 4; ++ks)
        #pragma unroll
        for (int mi = 0; mi < 3; ++mi)
            af[ks][mi] = *(const bf16x8*)(Ap + mi * 2048 + ks * 512);

    bf16x8 bX[4], bY[4], bZ[4];
    #define LOAD_B1(bp, ks, dst)                                              \
        _Pragma("unroll")                                                     \
        for (int ni = 0; ni < 4; ++ni)                                        \
            dst[ni] = *(const bf16x8*)((bp) + (ks) * 16384 + ni * 512);
    #define MFMA12(ks, bsrc, accv)                                            \
        _Pragma("unroll")                                                     \
        for (int mi = 0; mi < 3; ++mi)                                        \
            _Pragma("unroll")                                                 \
            for (int ni = 0; ni < 4; ++ni)                                    \
                accv[mi][ni] = __builtin_amdgcn_mfma_f32_16x16x32_bf16(       \
                    af[ks][mi], bsrc[ni], accv[mi][ni], 0, 0, 0);
    #define EPI1(h, accv)                                                     \
        _Pragma("unroll")                                                     \
        for (int ni = 0; ni < 4; ++ni) {                                      \
            int c = (wv * 8 + (h) * 4 + ni) * 16 + fr;                        \
            float bv = b1v[(h) * 4 + ni];                                     \
            _Pragma("unroll")                                                 \
            for (int mi = 0; mi < 3; ++mi)                                    \
                _Pragma("unroll")                                             \
                for (int r = 0; r < 4; ++r)                                   \
                    sH[(mi * 16 + q * 4 + r) * HPAD + c] =                    \
                        f2bf(fmaxf(accv[mi][ni][r] + bv, 0.f));               \
        }

    LOAD_B1(Bp0, 0, bX);
    LOAD_B1(Bp0, 1, bY);
    {
        f32x4 acc[3][4] = {};
        LOAD_B1(Bp0, 2, bZ);  MFMA12(0, bX, acc);
        LOAD_B1(Bp0, 3, bX);  MFMA12(1, bY, acc);
        LOAD_B1(Bp1, 0, bY);  MFMA12(2, bZ, acc);
        LOAD_B1(Bp1, 1, bZ);  MFMA12(3, bX, acc);
        EPI1(0, acc);
    }
    // layer-2 B prefetch pointers (issue first 3 before half-1 epilogue)
    const short* Bp2 = W2T + (size_t)(wv * 4) * 512 + lane * 8;
    f32x4 acc2[3][4] = {};
    bf16x8 bA[4], bB[4], bC[4], bD[4], aA[3], aB[3];
    #define LOAD_B2(ks, dst)                                                  \
        _Pragma("unroll")                                                     \
        for (int ni = 0; ni < 4; ++ni)                                        \
            dst[ni] = *(const bf16x8*)(Bp2 + (ks) * 8192 + ni * 512);
    {
        f32x4 acc[3][4] = {};
        LOAD_B1(Bp1, 2, bX);  MFMA12(0, bY, acc);
        LOAD_B1(Bp1, 3, bY);  MFMA12(1, bZ, acc);
        MFMA12(2, bX, acc);
        MFMA12(3, bY, acc);
        LOAD_B2(0, bA);
        LOAD_B2(1, bB);
        LOAD_B2(2, bC);
        EPI1(1, acc);
    }
    #undef LOAD_B1
    #undef MFMA12
    #undef EPI1

    __syncthreads();

    // ---- layer 2: depth-3 global B prefetch, depth-1 LDS A, 16 K-steps ----
    #define LOAD_A(ks, dst)                                                   \
        _Pragma("unroll")                                                     \
        for (int mi = 0; mi < 3; ++mi) {                                      \
            const short* hp = &sH[(mi * 16 + fr) * HPAD + (ks) * 32 + q * 8]; \
            short4 lo = *(const short4*)hp;                                   \
            short4 hi = *(const short4*)(hp + 4);                             \
            bf16x8 v;                                                         \
            v[0] = lo.x; v[1] = lo.y; v[2] = lo.z; v[3] = lo.w;               \
            v[4] = hi.x; v[5] = hi.y; v[6] = hi.z; v[7] = hi.w;               \
            dst[mi] = v;                                                      \
        }

    LOAD_A(0, aA);
    #pragma unroll
    for (int ks = 0; ks < 16; ++ks) {
        if (ks < 13) { LOAD_B2(ks + 3, bD); }
        if (ks < 15) { LOAD_A(ks + 1, aB); }
        #pragma unroll
        for (int mi = 0; mi < 3; ++mi)
            #pragma unroll
            for (int ni = 0; ni < 4; ++ni)
                acc2[mi][ni] = __builtin_amdgcn_mfma_f32_16x16x32_bf16(
                    aA[mi], bA[ni], acc2[mi][ni], 0, 0, 0);
        if (ks < 15) {
            #pragma unroll
            for (int i = 0; i < 4; ++i) { bA[i] = bB[i]; bB[i] = bC[i]; bC[i] = bD[i]; }
            #pragma unroll
            for (int i = 0; i < 3; ++i) aA[i] = aB[i];
        }
    }
    #undef LOAD_A
    #undef LOAD_B2

    // epilogue: bf16 short4 stores in permuted storage order
    float bv[4];
    #pragma unroll
    for (int ni = 0; ni < 4; ++ni)
        bv[ni] = b2[wv * 64 + ni * 16 + fr];
    #pragma unroll
    for (int mi = 0; mi < 3; ++mi)
        #pragma unroll
        for (int r = 0; r < 4; ++r) {
            int row = m0 + mi * 16 + q * 4 + r;
            short4 s;
            s.x = f2bf(acc2[mi][0][r] + bv[0]);
            s.y = f2bf(acc2[mi][1][r] + bv[1]);
            s.z = f2bf(acc2[mi][2][r] + bv[2]);
            s.w = f2bf(acc2[mi][3][r] + bv[3]);
            *(short4*)(out + (size_t)row * D_DIM + wv * 64 + fr * 4) = s;
        }
}

// ---------------------------------------------------------------------------
// Scoring. One block (4 waves) per sample. Branchless V-side from Vall
// (bf16 permuted); all row loads issued up front. Plain stores + separate
// reduce_kernel (agent-scope atomic fold cost +400us in round 7 — reverted).
// total_b = 2*( -logsig(clip(eu.ev)) - sum_k logsig(-clip(env_k.eu)) )
// ---------------------------------------------------------------------------
__device__ __forceinline__ float logsig_fast(float x) {
    float t = __expf(-fabsf(x));
    return fminf(x, 0.f) - __logf(1.f + t);
}
__device__ __forceinline__ float clip10(float x) {
    return fminf(fmaxf(x, -10.f), 10.f);
}

__global__ __launch_bounds__(256) void score_kernel(
    const int*   __restrict__ pos_u,
    const int*   __restrict__ pos_v,
    const int*   __restrict__ neg_v,
    const float* __restrict__ u_emb,
    const unsigned short* __restrict__ Vall,   // [100032][256] bf16, permuted
    const unsigned short* __restrict__ Ubuf,   // [MU_PAD][256] bf16, permuted
    float* __restrict__ partials)              // [B]
{
    const int b    = blockIdx.x;
    const int lane = threadIdx.x & 63;
    const int wv   = threadIdx.x >> 6;
    const int g    = lane >> 4;
    const int l    = lane & 15;
    const int w64  = (l >> 2) * 64;        // storage 64-col block
    const int s4   = (l & 3) * 4;          // fr base within block

    // Issue all row loads up front (one latency exposure).
    const int* nv = neg_v + (size_t)b * K_NEG + wv * 8;
    int ix0 = nv[g];
    int ix1 = nv[4 + g];
    const unsigned short* r0p = Vall + (size_t)ix0 * D_DIM + l * 16;
    const unsigned short* r1p = Vall + (size_t)ix1 * D_DIM + l * 16;
    u16x8 r0a = *(const u16x8*)r0p;
    u16x8 r0b = *(const u16x8*)(r0p + 8);
    u16x8 r1a = *(const u16x8*)r1p;
    u16x8 r1b = *(const u16x8*)(r1p + 8);
    u16x8 rpa, rpb;
    if (wv == 0) {
        const unsigned short* rpp = Vall + (size_t)pos_v[b] * D_DIM + l * 16;
        rpa = *(const u16x8*)rpp;
        rpb = *(const u16x8*)(rpp + 8);
    }

    // euf[i], i = j*4 + ni  <->  logical col w64 + ni*16 + s4 + j
    float euf[16];
    int pu = pos_u[b];
    if (pu < NR) {
        const float* eup = u_emb + (size_t)pu * D_DIM;
        #pragma unroll
        for (int n = 0; n < 4; ++n) {
            float4 v = *(const float4*)(eup + w64 + n * 16 + s4);
            euf[0 + n] = v.x; euf[4 + n] = v.y; euf[8 + n] = v.z; euf[12 + n] = v.w;
        }
    } else {
        const unsigned short* eup = Ubuf + (size_t)b * D_DIM + l * 16;
        u16x8 h0 = *(const u16x8*)eup;
        u16x8 h1 = *(const u16x8*)(eup + 8);
        #pragma unroll
        for (int i = 0; i < 8; ++i) { euf[i] = bf2f(h0[i]); euf[8 + i] = bf2f(h1[i]); }
    }

    float part = 0.f;

    float d0 = 0.f, d1 = 0.f;
    #pragma unroll
    for (int i = 0; i < 8; ++i) {
        d0 += euf[i] * bf2f(r0a[i]) + euf[8 + i] * bf2f(r0b[i]);
        d1 += euf[i] * bf2f(r1a[i]) + euf[8 + i] * bf2f(r1b[i]);
    }
    #pragma unroll
    for (int o = 1; o < 16; o <<= 1) {
        d0 += __shfl_xor(d0, o, 64);
        d1 += __shfl_xor(d1, o, 64);
    }
    part -= logsig_fast(-clip10(d0));
    part -= logsig_fast(-clip10(d1));

    if (wv == 0) {
        float dp = 0.f;
        #pragma unroll
        for (int i = 0; i < 8; ++i)
            dp += euf[i] * bf2f(rpa[i]) + euf[8 + i] * bf2f(rpb[i]);
        #pragma unroll
        for (int o = 1; o < 16; o <<= 1) dp += __shfl_xor(dp, o, 64);
        if (g == 0) part -= logsig_fast(clip10(dp));
    }

    float ws = part;
    #pragma unroll
    for (int o = 32; o; o >>= 1) ws += __shfl_xor(ws, o, 64);
    __shared__ float sp[4];
    if (lane == 0) sp[wv] = ws * 0.0625f;
    __syncthreads();
    if (threadIdx.x == 0)
        partials[b] = sp[0] + sp[1] + sp[2] + sp[3];
}

__global__ __launch_bounds__(256) void reduce_kernel(
    const float* __restrict__ partials, float* __restrict__ out)
{
    float s = 0.f;
    for (int i = threadIdx.x; i < B_SIZE; i += 256) s += partials[i];
    #pragma unroll
    for (int o = 32; o; o >>= 1) s += __shfl_xor(s, o, 64);
    __shared__ float sp[4];
    if ((threadIdx.x & 63) == 0) sp[threadIdx.x >> 6] = s;
    __syncthreads();
    if (threadIdx.x == 0)
        out[0] = (sp[0] + sp[1] + sp[2] + sp[3]) * (2.0f / (float)B_SIZE);
}

// ---------------------------------------------------------------------------
extern "C" void kernel_launch(void* const* d_in, const int* in_sizes, int n_in,
                              void* d_out, int out_size, void* d_ws, size_t ws_size,
                              hipStream_t stream) {
    const int*   pos_u  = (const int*)  d_in[0];
    const int*   pos_v  = (const int*)  d_in[1];
    const int*   neg_v  = (const int*)  d_in[2];
    const float* u_emb  = (const float*)d_in[3];
    const float* v_emb  = (const float*)d_in[4];
    const float* stoich = (const float*)d_in[5];
    const float* tw1    = (const float*)d_in[6];
    const float* tb1    = (const float*)d_in[7];
    const float* tw2    = (const float*)d_in[8];
    const float* tb2    = (const float*)d_in[9];
    const float* cw1    = (const float*)d_in[10];
    const float* cb1    = (const float*)d_in[11];
    const float* cw2    = (const float*)d_in[12];
    const float* cb2    = (const float*)d_in[13];
    float* out = (float*)d_out;

    // workspace layout (bytes, 16B aligned)
    char* ws = (char*)d_ws;
    short* Xbf   = (short*)(ws);                      // MC_PAD*128*2  = 10,248,192
    short* Xu    = (short*)(ws + 10248192);           // MU_PAD*128*2  =  2,101,248
    short* W1T_t = (short*)(ws + 12349440);           //   512*128*2   =    131,072
    short* W1T_c = (short*)(ws + 12480512);           //                   131,072
    short* W2T_t = (short*)(ws + 12611584);           //   256*512*2   =    262,144
    short* W2T_c = (short*)(ws + 12873728);           //                   262,144
    short* Vall  = (short*)(ws + 13135872);           // 100032*256*2  = 51,216,384
    short* Ubuf  = (short*)(ws + 64352256);           // MU_PAD*256*2  =  4,202,496
    float* parts = (float*)(ws + 68554752);           //  8192*4
    short* tab_c = Vall + (size_t)NR * D_DIM;         // MLP c-table inside Vall

    dim3 blk(256);

    // merged prep (1 launch): v_emb bf16 conversion + A-side + weights
    prep_kernel<<<dim3((N_VC + N_CONV + N_XU + N_TR) / 256), blk, 0, stream>>>(
        stoich, pos_u, v_emb, tw1, cw1, tw2, cw2,
        Vall, Xbf, Xu, W1T_t, W1T_c, W2T_t, W2T_c);

    // both fused MLP passes in one launch (c-side: 834 blocks, u-side: 171)
    fused_mlp_kernel<<<dim3(CBLK + UBLK), blk, 0, stream>>>(
        Xbf, W1T_c, cb1, W2T_c, cb2, tab_c,
        Xu,  W1T_t, tb1, W2T_t, tb2, Ubuf);

    // scoring (branchless V-side) + separate reduce
    score_kernel<<<dim3(B_SIZE), blk, 0, stream>>>(
        pos_u, pos_v, neg_v, u_emb,
        (const unsigned short*)Vall, (const unsigned short*)Ubuf, parts);
    reduce_kernel<<<dim3(1), blk, 0, stream>>>(parts, out);
}

// Round 9
// 290.614 us; speedup vs baseline: 2.3577x; 1.0161x over previous
//
#include <hip/hip_runtime.h>
#include <hip/hip_bf16.h>
#include <math.h>

// Problem constants (match reference)
#define V_SIZE 100000
#define D_DIM  256
#define S_DIM  128
#define H_DIM  512
#define B_SIZE 8192
#define K_NEG  32
#define NR     60000           // NUM_REGULAR
#define NMOD   (V_SIZE - NR)   // 40000 modified words

// MLP tiling (TM=48 = best; TM=32 regressed -> keep 48)
#define TM     48              // rows per block (3 x 16)
#define CBLK   834             // ceil(40000/48)
#define UBLK   171             // ceil(8192/48)
#define MC_PAD (CBLK * TM)     // 40032 padded c-side rows
#define MU_PAD (UBLK * TM)     // 8208  padded u-side rows
// LDS H row stride (shorts). 516: layer-1 b16 writes land 2 lanes/bank
// (free); 1032-B rows keep 8-B alignment for ds_read_b64 in layer 2.
#define HPAD   516

typedef __attribute__((ext_vector_type(8))) short bf16x8;   // 8 bf16 = 4 VGPRs
typedef __attribute__((ext_vector_type(8))) unsigned short u16x8;
typedef __attribute__((ext_vector_type(4))) float f32x4;

static __device__ __forceinline__ short f2bf(float f) {
    unsigned u = __builtin_bit_cast(unsigned, f);
    unsigned r = (u + 0x7fffu + ((u >> 16) & 1u)) >> 16;   // RNE
    return (short)r;
}
static __device__ __forceinline__ float bf2f(unsigned short h) {
    return __builtin_bit_cast(float, ((unsigned)h) << 16);
}

// ---------------------------------------------------------------------------
// Vall STORAGE (bf16, permuted columns), rows 0..100032:
//   rows [0,60000)       = bf16(v_emb)     (conv blocks in fused launch)
//   rows [60000,100032)  = MLP c-table     (MLP blocks in fused launch)
//   storage pos p = wv*64 + fr*4 + ni  <->  logical col c = wv*64 + ni*16 + fr
// Dot products are permutation-invariant; score indexes Vall[ix] directly.
// Ubuf (u-side MLP rows) uses the same permuted layout.
// Lessons encoded here:
//  - r7: NO agent-scope atomic reduction fold (per-XCD L2 non-coherence ->
//    +400us of cache maintenance across 8192 blocks). Separate reduce_kernel.
//  - r8: hand-scheduled L1 pipeline was neutral -> keep compiler-scheduled.
//  - r9: v_emb conversion rides in the fused launch as tail-filling
//    grid-stride blocks (overlaps the MLP tail; disjoint Vall row ranges).
// ---------------------------------------------------------------------------

#define N_VC   (NR * D_DIM / 4)               // 3,840,000 short4 elems
#define N_CONV (MC_PAD * S_DIM / 4)           // 1,281,024
#define N_XU   (MU_PAD * S_DIM / 4)           //   262,656
#define N_TR   393216
#define NCONVB 1024                           // conv blocks appended to fused

__global__ __launch_bounds__(256) void prep_kernel(
    const float* __restrict__ stoich, const int* __restrict__ pos_u,
    const float* __restrict__ tw1, const float* __restrict__ cw1,
    const float* __restrict__ tw2, const float* __restrict__ cw2,
    short* __restrict__ xc, short* __restrict__ xu,
    short* __restrict__ W1T_t, short* __restrict__ W1T_c,
    short* __restrict__ W2T_t, short* __restrict__ W2T_c)
{
    int t = blockIdx.x * 256 + threadIdx.x;
    if (t < N_CONV + N_XU) {
        // A-side fragment-linear bf16 (short4 per thread, j0 in {0,4})
        const bool cside = t < N_CONV;
        const int e    = (cside ? t : t - N_CONV) * 4;
        const int j0   = e & 7;
        const int lane = (e >> 3) & 63;
        const int ks   = (e >> 9) & 3;
        const int rt   = e >> 11;
        const int row  = rt * 16 + (lane & 15);
        const int k    = ks * 32 + (lane >> 4) * 8 + j0;
        short4 o = {0, 0, 0, 0};
        if (cside) {
            if (row < NMOD) {
                const float4 v = *(const float4*)(stoich + (size_t)(NR + row) * S_DIM + k);
                o.x = f2bf(v.x); o.y = f2bf(v.y); o.z = f2bf(v.z); o.w = f2bf(v.w);
            }
            ((short4*)xc)[t] = o;
        } else {
            if (row < B_SIZE) {
                int pu = pos_u[row];
                const float4 v = *(const float4*)(stoich + (size_t)pu * S_DIM + k);
                o.x = f2bf(v.x); o.y = f2bf(v.y); o.z = f2bf(v.z); o.w = f2bf(v.w);
            }
            ((short4*)xu)[t - N_CONV] = o;
        }
    } else {
        int t3 = t - (N_CONV + N_XU);                 // [0, 393216)
        if (t3 < 131072) {                            // W1 pair (65536 each)
            const float* src = (t3 < 65536) ? tw1 : cw1;
            short*       dst = (t3 < 65536) ? W1T_t : W1T_c;
            int t4 = t3 & 65535;
            int j = t4 & 7, lane = (t4 >> 3) & 63;
            int nt = (t4 >> 9) & 31, ks = (t4 >> 14) & 3;
            int k = ks * 32 + (lane >> 4) * 8 + j, n = nt * 16 + (lane & 15);
            dst[t4] = f2bf(src[(size_t)k * H_DIM + n]);
        } else {                                      // W2 pair (131072 each)
            int t5 = t3 - 131072;
            const float* src = (t5 < 131072) ? tw2 : cw2;
            short*       dst = (t5 < 131072) ? W2T_t : W2T_c;
            int t4 = t5 & 131071;
            int j = t4 & 7, lane = (t4 >> 3) & 63;
            int nt = (t4 >> 9) & 15, ks = (t4 >> 13) & 15;
            int k = ks * 32 + (lane >> 4) * 8 + j, n = nt * 16 + (lane & 15);
            dst[t4] = f2bf(src[(size_t)k * D_DIM + n]);
        }
    }
}

// ---------------------------------------------------------------------------
// Fused 2-layer MLP + tail-filling v_emb conversion, one launch.
// Blocks [0, CBLK+UBLK): MLP tiles (round-6 structure — compiler-scheduled
// layer 1, depth-3 layer-2 B prefetch issued pre-barrier).
// Blocks [CBLK+UBLK, +NCONVB): grid-stride v_emb -> Vall bf16 permuted
// conversion; these dispatch after the MLP blocks and fill the tail.
// Verified MFMA layouts (m89/m91): A[m=lane&15][k=q*8+j]; B^T row (lane&15)
// supplies B[k][n=lane&15]; D: col=lane&15, row=q*4+reg.
// ---------------------------------------------------------------------------
__global__ __launch_bounds__(256, 3) void fused_mlp_kernel(
    const short* __restrict__ Xc,  const short* __restrict__ W1c,
    const float* __restrict__ b1c, const short* __restrict__ W2c,
    const float* __restrict__ b2c, short* __restrict__ outc,
    const short* __restrict__ Xu,  const short* __restrict__ W1u,
    const float* __restrict__ b1u, const short* __restrict__ W2u,
    const float* __restrict__ b2u, short* __restrict__ outu,
    const float* __restrict__ v_emb, short* __restrict__ vall)
{
    __shared__ short sH[TM * HPAD];   // 49,536 B -> 3 blocks/CU

    const int blk = blockIdx.x;
    if (blk >= CBLK + UBLK) {
        // ---- v_emb -> Vall bf16 permuted, grid-stride (tail filler) ----
        int tid = (blk - (CBLK + UBLK)) * 256 + threadIdx.x;
        for (int t = tid; t < N_VC; t += NCONVB * 256) {
            int r  = t >> 6;
            int fr = t & 15;
            int wvv = (t & 63) >> 4;
            const float* rp = v_emb + (size_t)r * D_DIM + wvv * 64 + fr;
            short4 o;
            o.x = f2bf(rp[0]);  o.y = f2bf(rp[16]);
            o.z = f2bf(rp[32]); o.w = f2bf(rp[48]);
            ((short4*)vall)[t] = o;
        }
        return;
    }

    const short *A, *W1T, *W2T; const float *b1, *b2; short* out;
    int m0, rtb;
    if (blk < CBLK) { A = Xc; W1T = W1c; b1 = b1c; W2T = W2c; b2 = b2c;
                      out = outc; m0 = blk * TM; rtb = blk * 3; }
    else            { A = Xu; W1T = W1u; b1 = b1u; W2T = W2u; b2 = b2u;
                      out = outu; m0 = (blk - CBLK) * TM; rtb = (blk - CBLK) * 3; }

    const int lane = threadIdx.x & 63;
    const int wv   = threadIdx.x >> 6;
    const int fr   = lane & 15;
    const int q    = lane >> 4;

    // ---- layer 1 ----
    // A fragments: XF[((rtb+mi)*4 + ks)*512 + lane*8], contiguous per wave
    const short* Ap = A + (size_t)rtb * 2048 + lane * 8;
    bf16x8 af[4][3];
    #pragma unroll
    for (int ks = 0; ks < 4; ++ks)
        #pragma unroll
        for (int mi = 0; mi < 3; ++mi)
            af[ks][mi] = *(const bf16x8*)(Ap + mi * 2048 + ks * 512);

    #pragma unroll
    for (int half = 0; half < 2; ++half) {
        const int nt0 = wv * 8 + half * 4;            // n-tile base
        const short* Bp = W1T + (size_t)nt0 * 512 + lane * 8;
        f32x4 acc[3][4] = {};
        #pragma unroll
        for (int ks = 0; ks < 4; ++ks) {
            bf16x8 bfr[4];
            #pragma unroll
            for (int ni = 0; ni < 4; ++ni)
                bfr[ni] = *(const bf16x8*)(Bp + ks * 16384 + ni * 512);
            #pragma unroll
            for (int mi = 0; mi < 3; ++mi)
                #pragma unroll
                for (int ni = 0; ni < 4; ++ni)
                    acc[mi][ni] = __builtin_amdgcn_mfma_f32_16x16x32_bf16(
                        af[ks][mi], bfr[ni], acc[mi][ni], 0, 0, 0);
        }
        #pragma unroll
        for (int ni = 0; ni < 4; ++ni) {
            int c = (nt0 + ni) * 16 + fr;
            float bv = b1[c];
            #pragma unroll
            for (int mi = 0; mi < 3; ++mi)
                #pragma unroll
                for (int r = 0; r < 4; ++r)
                    sH[(mi * 16 + q * 4 + r) * HPAD + c] =
                        f2bf(fmaxf(acc[mi][ni][r] + bv, 0.f));
        }
    }

    // ---- layer 2: depth-3 global B prefetch (first 3 pre-barrier) ----
    // B fragments: W2F[((ks*16 + wv*4+ni)*64 + lane)*8]
    const short* Bp2 = W2T + (size_t)(wv * 4) * 512 + lane * 8;
    f32x4 acc2[3][4] = {};
    bf16x8 bA[4], bB[4], bC[4], bD[4], aA[3], aB[3];

    #define LOAD_B2(ks, dst)                                                  \
        _Pragma("unroll")                                                     \
        for (int ni = 0; ni < 4; ++ni)                                        \
            dst[ni] = *(const bf16x8*)(Bp2 + (ks) * 8192 + ni * 512);
    #define LOAD_A(ks, dst)                                                   \
        _Pragma("unroll")                                                     \
        for (int mi = 0; mi < 3; ++mi) {                                      \
            const short* hp = &sH[(mi * 16 + fr) * HPAD + (ks) * 32 + q * 8]; \
            short4 lo = *(const short4*)hp;                                   \
            short4 hi = *(const short4*)(hp + 4);                             \
            bf16x8 v;                                                         \
            v[0] = lo.x; v[1] = lo.y; v[2] = lo.z; v[3] = lo.w;               \
            v[4] = hi.x; v[5] = hi.y; v[6] = hi.z; v[7] = hi.w;               \
            dst[mi] = v;                                                      \
        }

    LOAD_B2(0, bA);
    LOAD_B2(1, bB);
    LOAD_B2(2, bC);
    __syncthreads();
    LOAD_A(0, aA);
    #pragma unroll
    for (int ks = 0; ks < 16; ++ks) {
        if (ks < 13) { LOAD_B2(ks + 3, bD); }
        if (ks < 15) { LOAD_A(ks + 1, aB); }
        #pragma unroll
        for (int mi = 0; mi < 3; ++mi)
            #pragma unroll
            for (int ni = 0; ni < 4; ++ni)
                acc2[mi][ni] = __builtin_amdgcn_mfma_f32_16x16x32_bf16(
                    aA[mi], bA[ni], acc2[mi][ni], 0, 0, 0);
        if (ks < 15) {
            #pragma unroll
            for (int i = 0; i < 4; ++i) { bA[i] = bB[i]; bB[i] = bC[i]; bC[i] = bD[i]; }
            #pragma unroll
            for (int i = 0; i < 3; ++i) aA[i] = aB[i];
        }
    }
    #undef LOAD_A
    #undef LOAD_B2

    // epilogue: bf16 short4 stores in permuted storage order
    float bv[4];
    #pragma unroll
    for (int ni = 0; ni < 4; ++ni)
        bv[ni] = b2[wv * 64 + ni * 16 + fr];
    #pragma unroll
    for (int mi = 0; mi < 3; ++mi)
        #pragma unroll
        for (int r = 0; r < 4; ++r) {
            int row = m0 + mi * 16 + q * 4 + r;
            short4 s;
            s.x = f2bf(acc2[mi][0][r] + bv[0]);
            s.y = f2bf(acc2[mi][1][r] + bv[1]);
            s.z = f2bf(acc2[mi][2][r] + bv[2]);
            s.w = f2bf(acc2[mi][3][r] + bv[3]);
            *(short4*)(out + (size_t)row * D_DIM + wv * 64 + fr * 4) = s;
        }
}

// ---------------------------------------------------------------------------
// Scoring. One block (4 waves) per sample. Branchless V-side from Vall
// (bf16 permuted); all row loads issued up front. Plain stores + separate
// reduce_kernel (agent-scope atomic fold cost +400us in round 7 — reverted).
// total_b = 2*( -logsig(clip(eu.ev)) - sum_k logsig(-clip(env_k.eu)) )
// ---------------------------------------------------------------------------
__device__ __forceinline__ float logsig_fast(float x) {
    float t = __expf(-fabsf(x));
    return fminf(x, 0.f) - __logf(1.f + t);
}
__device__ __forceinline__ float clip10(float x) {
    return fminf(fmaxf(x, -10.f), 10.f);
}

__global__ __launch_bounds__(256) void score_kernel(
    const int*   __restrict__ pos_u,
    const int*   __restrict__ pos_v,
    const int*   __restrict__ neg_v,
    const float* __restrict__ u_emb,
    const unsigned short* __restrict__ Vall,   // [100032][256] bf16, permuted
    const unsigned short* __restrict__ Ubuf,   // [MU_PAD][256] bf16, permuted
    float* __restrict__ partials)              // [B]
{
    const int b    = blockIdx.x;
    const int lane = threadIdx.x & 63;
    const int wv   = threadIdx.x >> 6;
    const int g    = lane >> 4;
    const int l    = lane & 15;
    const int w64  = (l >> 2) * 64;        // storage 64-col block
    const int s4   = (l & 3) * 4;          // fr base within block

    // Issue all row loads up front (one latency exposure).
    const int* nv = neg_v + (size_t)b * K_NEG + wv * 8;
    int ix0 = nv[g];
    int ix1 = nv[4 + g];
    const unsigned short* r0p = Vall + (size_t)ix0 * D_DIM + l * 16;
    const unsigned short* r1p = Vall + (size_t)ix1 * D_DIM + l * 16;
    u16x8 r0a = *(const u16x8*)r0p;
    u16x8 r0b = *(const u16x8*)(r0p + 8);
    u16x8 r1a = *(const u16x8*)r1p;
    u16x8 r1b = *(const u16x8*)(r1p + 8);
    u16x8 rpa, rpb;
    if (wv == 0) {
        const unsigned short* rpp = Vall + (size_t)pos_v[b] * D_DIM + l * 16;
        rpa = *(const u16x8*)rpp;
        rpb = *(const u16x8*)(rpp + 8);
    }

    // euf[i], i = j*4 + ni  <->  logical col w64 + ni*16 + s4 + j
    float euf[16];
    int pu = pos_u[b];
    if (pu < NR) {
        const float* eup = u_emb + (size_t)pu * D_DIM;
        #pragma unroll
        for (int n = 0; n < 4; ++n) {
            float4 v = *(const float4*)(eup + w64 + n * 16 + s4);
            euf[0 + n] = v.x; euf[4 + n] = v.y; euf[8 + n] = v.z; euf[12 + n] = v.w;
        }
    } else {
        const unsigned short* eup = Ubuf + (size_t)b * D_DIM + l * 16;
        u16x8 h0 = *(const u16x8*)eup;
        u16x8 h1 = *(const u16x8*)(eup + 8);
        #pragma unroll
        for (int i = 0; i < 8; ++i) { euf[i] = bf2f(h0[i]); euf[8 + i] = bf2f(h1[i]); }
    }

    float part = 0.f;

    float d0 = 0.f, d1 = 0.f;
    #pragma unroll
    for (int i = 0; i < 8; ++i) {
        d0 += euf[i] * bf2f(r0a[i]) + euf[8 + i] * bf2f(r0b[i]);
        d1 += euf[i] * bf2f(r1a[i]) + euf[8 + i] * bf2f(r1b[i]);
    }
    #pragma unroll
    for (int o = 1; o < 16; o <<= 1) {
        d0 += __shfl_xor(d0, o, 64);
        d1 += __shfl_xor(d1, o, 64);
    }
    part -= logsig_fast(-clip10(d0));
    part -= logsig_fast(-clip10(d1));

    if (wv == 0) {
        float dp = 0.f;
        #pragma unroll
        for (int i = 0; i < 8; ++i)
            dp += euf[i] * bf2f(rpa[i]) + euf[8 + i] * bf2f(rpb[i]);
        #pragma unroll
        for (int o = 1; o < 16; o <<= 1) dp += __shfl_xor(dp, o, 64);
        if (g == 0) part -= logsig_fast(clip10(dp));
    }

    float ws = part;
    #pragma unroll
    for (int o = 32; o; o >>= 1) ws += __shfl_xor(ws, o, 64);
    __shared__ float sp[4];
    if (lane == 0) sp[wv] = ws * 0.0625f;
    __syncthreads();
    if (threadIdx.x == 0)
        partials[b] = sp[0] + sp[1] + sp[2] + sp[3];
}

__global__ __launch_bounds__(256) void reduce_kernel(
    const float* __restrict__ partials, float* __restrict__ out)
{
    float s = 0.f;
    for (int i = threadIdx.x; i < B_SIZE; i += 256) s += partials[i];
    #pragma unroll
    for (int o = 32; o; o >>= 1) s += __shfl_xor(s, o, 64);
    __shared__ float sp[4];
    if ((threadIdx.x & 63) == 0) sp[threadIdx.x >> 6] = s;
    __syncthreads();
    if (threadIdx.x == 0)
        out[0] = (sp[0] + sp[1] + sp[2] + sp[3]) * (2.0f / (float)B_SIZE);
}

// ---------------------------------------------------------------------------
extern "C" void kernel_launch(void* const* d_in, const int* in_sizes, int n_in,
                              void* d_out, int out_size, void* d_ws, size_t ws_size,
                              hipStream_t stream) {
    const int*   pos_u  = (const int*)  d_in[0];
    const int*   pos_v  = (const int*)  d_in[1];
    const int*   neg_v  = (const int*)  d_in[2];
    const float* u_emb  = (const float*)d_in[3];
    const float* v_emb  = (const float*)d_in[4];
    const float* stoich = (const float*)d_in[5];
    const float* tw1    = (const float*)d_in[6];
    const float* tb1    = (const float*)d_in[7];
    const float* tw2    = (const float*)d_in[8];
    const float* tb2    = (const float*)d_in[9];
    const float* cw1    = (const float*)d_in[10];
    const float* cb1    = (const float*)d_in[11];
    const float* cw2    = (const float*)d_in[12];
    const float* cb2    = (const float*)d_in[13];
    float* out = (float*)d_out;

    // workspace layout (bytes, 16B aligned)
    char* ws = (char*)d_ws;
    short* Xbf   = (short*)(ws);                      // MC_PAD*128*2  = 10,248,192
    short* Xu    = (short*)(ws + 10248192);           // MU_PAD*128*2  =  2,101,248
    short* W1T_t = (short*)(ws + 12349440);           //   512*128*2   =    131,072
    short* W1T_c = (short*)(ws + 12480512);           //                   131,072
    short* W2T_t = (short*)(ws + 12611584);           //   256*512*2   =    262,144
    short* W2T_c = (short*)(ws + 12873728);           //                   262,144
    short* Vall  = (short*)(ws + 13135872);           // 100032*256*2  = 51,216,384
    short* Ubuf  = (short*)(ws + 64352256);           // MU_PAD*256*2  =  4,202,496
    float* parts = (float*)(ws + 68554752);           //  8192*4
    short* tab_c = Vall + (size_t)NR * D_DIM;         // MLP c-table inside Vall

    dim3 blk(256);

    // prep (1 launch): A-side + weight transposes only (v-conv moved to fused)
    prep_kernel<<<dim3((N_CONV + N_XU + N_TR) / 256), blk, 0, stream>>>(
        stoich, pos_u, tw1, cw1, tw2, cw2,
        Xbf, Xu, W1T_t, W1T_c, W2T_t, W2T_c);

    // fused: 1005 MLP blocks + 1024 tail-filling v_emb conversion blocks
    fused_mlp_kernel<<<dim3(CBLK + UBLK + NCONVB), blk, 0, stream>>>(
        Xbf, W1T_c, cb1, W2T_c, cb2, tab_c,
        Xu,  W1T_t, tb1, W2T_t, tb2, Ubuf,
        v_emb, Vall);

    // scoring (branchless V-side) + separate reduce
    score_kernel<<<dim3(B_SIZE), blk, 0, stream>>>(
        pos_u, pos_v, neg_v, u_emb,
        (const unsigned short*)Vall, (const unsigned short*)Ubuf, parts);
    reduce_kernel<<<dim3(1), blk, 0, stream>>>(parts, out);
}